// Round 6
// baseline (2574.770 us; speedup 1.0000x reference)
//
#include <hip/hip_runtime.h>
#include <math.h>

#define N_NODES 50000
#define N_EDGES 800000
#define D_IN 64
#define D_HID 128
#define SCAN_B 256
#define N_SB ((N_NODES + SCAN_B - 1) / SCAN_B)  // 196
#define NPB 256                                  // nodes per bucket
#define NB ((N_NODES + NPB - 1) / NPB)           // 196 buckets
#define P1_BLOCKS 256
#define EPB (N_EDGES / P1_BLOCKS)                // 3125 edges per pass-1 block

typedef unsigned short u16;
typedef unsigned int u32;

__device__ __forceinline__ float bf2f(u16 u) {
    u32 x = ((u32)u) << 16;
    float f; __builtin_memcpy(&f, &x, 4); return f;
}
__device__ __forceinline__ u16 f2bf(float f) {  // round-to-nearest-even
    u32 x; __builtin_memcpy(&x, &f, 4);
    x += 0x7fffu + ((x >> 16) & 1u);
    return (u16)(x >> 16);
}
__device__ __forceinline__ u32 pk2(float a, float b) {  // pack 2 bf16 into u32
    return (u32)f2bf(a) | ((u32)f2bf(b) << 16);
}

// ============================ CSR build ============================

__global__ void count_kernel(const int* __restrict__ dst, int* __restrict__ deg, int E) {
    int i = blockIdx.x * blockDim.x + threadIdx.x;
    if (i < E) atomicAdd(&deg[dst[i]], 1);
}

__global__ __launch_bounds__(SCAN_B) void scan_reduce_kernel(const int* __restrict__ deg,
                                                             int* __restrict__ bsum) {
    __shared__ int s[SCAN_B];
    int i = blockIdx.x * SCAN_B + threadIdx.x;
    int v = (i < N_NODES) ? deg[i] : 0;
    s[threadIdx.x] = v;
    __syncthreads();
    #pragma unroll
    for (int o = SCAN_B / 2; o > 0; o >>= 1) {
        if (threadIdx.x < o) s[threadIdx.x] += s[threadIdx.x + o];
        __syncthreads();
    }
    if (threadIdx.x == 0) bsum[blockIdx.x] = s[0];
}

__global__ __launch_bounds__(SCAN_B) void scan_sums_kernel(const int* __restrict__ bsum,
                                                           int* __restrict__ boff) {
    __shared__ int s[SCAN_B];
    int t = threadIdx.x;
    int v = (t < N_SB) ? bsum[t] : 0;
    s[t] = v;
    __syncthreads();
    #pragma unroll
    for (int o = 1; o < SCAN_B; o <<= 1) {
        int u = (t >= o) ? s[t - o] : 0;
        __syncthreads();
        s[t] += u;
        __syncthreads();
    }
    if (t < N_SB) boff[t] = s[t] - v;  // exclusive
}

__global__ __launch_bounds__(SCAN_B) void scan_write_kernel(const int* __restrict__ deg,
                                                            const int* __restrict__ boff,
                                                            int* __restrict__ off) {
    __shared__ int s[SCAN_B];
    int t = threadIdx.x;
    int i = blockIdx.x * SCAN_B + t;
    int v = (i < N_NODES) ? deg[i] : 0;
    s[t] = v;
    __syncthreads();
    #pragma unroll
    for (int o = 1; o < SCAN_B; o <<= 1) {
        int u = (t >= o) ? s[t - o] : 0;
        __syncthreads();
        s[t] += u;
        __syncthreads();
    }
    int incl = s[t] + boff[blockIdx.x];
    if (i < N_NODES) off[i] = incl - v;
    if (i == N_NODES - 1) off[N_NODES] = incl;
}

// ==================== binned scatter (2-pass) ====================
__global__ void bin_init_kernel(const int* __restrict__ off, int* __restrict__ gcur) {
    int b = threadIdx.x;
    if (b < NB) gcur[b] = off[min(b * NPB, N_NODES)];
}

__global__ __launch_bounds__(256) void bin_pass1_kernel(const int* __restrict__ src,
                                                        const int* __restrict__ dst,
                                                        int* __restrict__ gcur,
                                                        int2* __restrict__ ebuf) {
    __shared__ int hist[NB];
    __shared__ int base[NB];
    const int tid = threadIdx.x;
    const int e0 = blockIdx.x * EPB, e1 = e0 + EPB;
    for (int b = tid; b < NB; b += 256) hist[b] = 0;
    __syncthreads();
    for (int i = e0 + tid; i < e1; i += 256)
        atomicAdd(&hist[dst[i] >> 8], 1);
    __syncthreads();
    for (int b = tid; b < NB; b += 256) {
        base[b] = atomicAdd(&gcur[b], hist[b]);
        hist[b] = 0;  // reuse as block-local cursor
    }
    __syncthreads();
    for (int i = e0 + tid; i < e1; i += 256) {
        int d = dst[i];
        int b = d >> 8;
        int slot = base[b] + atomicAdd(&hist[b], 1);
        ebuf[slot] = make_int2(src[i], d);
    }
}

__global__ __launch_bounds__(256) void bin_pass2_kernel(const int* __restrict__ off,
                                                        const int2* __restrict__ ebuf,
                                                        int* __restrict__ esrc) {
    __shared__ int soff[NPB];
    __shared__ int cur[NPB];
    const int b = blockIdx.x;
    const int tid = threadIdx.x;
    const int n0 = b * NPB;
    soff[tid] = off[min(n0 + tid, N_NODES)];
    cur[tid] = 0;
    __syncthreads();
    const int e0 = soff[0];
    const int e1 = off[min(n0 + NPB, N_NODES)];
    for (int i = e0 + tid; i < e1; i += 256) {
        int2 p = ebuf[i];
        int dl = p.y - n0;
        int slot = soff[dl] + atomicAdd(&cur[dl], 1);
        esrc[slot] = p.x;
    }
}

// ==================== x -> bf16 convert ====================
__global__ __launch_bounds__(256) void xcvt_kernel(const float* __restrict__ x,
                                                   u16* __restrict__ xb) {
    int i = blockIdx.x * 256 + threadIdx.x;  // one float4 per thread
    if (i < N_NODES * D_IN / 4) {
        float4 v = ((const float4*)x)[i];
        u32 lo = pk2(v.x, v.y), hi = pk2(v.z, v.w);
        ((uint2*)xb)[i] = make_uint2(lo, hi);
    }
}

// ==================== softmax aggregation + residual (bf16 in/out) ============
// One wave per node, lane = channel. No-max softmax (values O(1), fp32-safe).
// 8-edge unroll -> 8 outstanding 128B row-gathers from a 6.4MB L2-resident array.
__global__ __launch_bounds__(256) void agg_kernel(const u16* __restrict__ x,
                                                  const int* __restrict__ off,
                                                  const int* __restrict__ esrc,
                                                  u16* __restrict__ h) {
    int node = blockIdx.x * 4 + (threadIdx.x >> 6);
    int lane = threadIdx.x & 63;
    if (node >= N_NODES) return;
    float xn = bf2f(x[(size_t)node * D_IN + lane]);  // residual
    int jb = off[node], je = off[node + 1];
    float s = 0.f, t = 0.f;
    int j = jb;
    for (; j + 8 <= je; j += 8) {
        int idx[8];
        #pragma unroll
        for (int u = 0; u < 8; u++) idx[u] = esrc[j + u];
        u16 v[8];
        #pragma unroll
        for (int u = 0; u < 8; u++) v[u] = x[(size_t)idx[u] * D_IN + lane];
        #pragma unroll
        for (int u = 0; u < 8; u++) {
            float msg = fmaxf(bf2f(v[u]), 0.f) + 1e-7f;
            float p = __expf(msg);
            s += p;
            t = fmaf(msg, p, t);
        }
    }
    for (; j < je; j++) {
        int sv = esrc[j];
        float msg = fmaxf(bf2f(x[(size_t)sv * D_IN + lane]), 0.f) + 1e-7f;
        float p = __expf(msg);
        s += p;
        t = fmaf(msg, p, t);
    }
    float agg = t / (s + 1e-16f);    // deg==0 -> 0
    h[(size_t)node * D_IN + lane] = f2bf(agg + xn);
}

// ==================== GEMM1 + fused BN stats ====================
// h1[M,128] = A[M,64](bf16) @ W[64,128] + b ; A staged in LDS (fp32, padded).
__global__ __launch_bounds__(256) void gemm1_kernel(const u16* __restrict__ A,
                                                    const float* __restrict__ W,
                                                    const float* __restrict__ bias,
                                                    u16* __restrict__ Bout,
                                                    float* __restrict__ S,
                                                    float* __restrict__ Q) {
    __shared__ float sW[64 * 128];   // 32 KB; reused as reduction space in epilogue
    __shared__ float sA[64 * 65];    // 16.6 KB, +1 pad kills bank aliasing
    const int tid = threadIdx.x;
    const int row0g = blockIdx.x * 64;
    {
        const float4* Wv = (const float4*)W;
        float4* sWv = (float4*)sW;
        #pragma unroll
        for (int i = tid; i < 64 * 128 / 4; i += 256) sWv[i] = Wv[i];
        // stage A: 64 rows x 32 uints (2 bf16 each), coalesced
        const u32* Au = (const u32*)A;
        #pragma unroll
        for (int i = tid; i < 64 * 32; i += 256) {
            int row = i >> 5, cu = i & 31;
            int grow = min(row0g + row, N_NODES - 1);
            u32 u = Au[(size_t)grow * 32 + cu];
            sA[row * 65 + cu * 2]     = bf2f((u16)u);
            sA[row * 65 + cu * 2 + 1] = bf2f((u16)(u >> 16));
        }
    }
    __syncthreads();
    const int tx = tid & 15;   // 16 col-groups of 8 -> 128 cols
    const int ty = tid >> 4;   // 16 row-groups of 4 -> 64 rows
    const int c0 = tx * 8;
    const int ty4 = ty * 4;
    const int row0 = row0g + ty4;

    float acc[4][8];
    #pragma unroll
    for (int i = 0; i < 4; i++)
        #pragma unroll
        for (int j = 0; j < 8; j++) acc[i][j] = bias[c0 + j];

    #pragma unroll
    for (int k = 0; k < 64; k += 4) {
        #pragma unroll
        for (int kk = 0; kk < 4; kk++) {
            float4 w0 = *(const float4*)&sW[(k + kk) * 128 + c0];
            float4 w1 = *(const float4*)&sW[(k + kk) * 128 + c0 + 4];
            #pragma unroll
            for (int i = 0; i < 4; i++) {
                float ai = sA[(ty4 + i) * 65 + k + kk];  // 16-lane broadcast
                acc[i][0] = fmaf(ai, w0.x, acc[i][0]);
                acc[i][1] = fmaf(ai, w0.y, acc[i][1]);
                acc[i][2] = fmaf(ai, w0.z, acc[i][2]);
                acc[i][3] = fmaf(ai, w0.w, acc[i][3]);
                acc[i][4] = fmaf(ai, w1.x, acc[i][4]);
                acc[i][5] = fmaf(ai, w1.y, acc[i][5]);
                acc[i][6] = fmaf(ai, w1.z, acc[i][6]);
                acc[i][7] = fmaf(ai, w1.w, acc[i][7]);
            }
        }
    }
    // store bf16 tile
    #pragma unroll
    for (int i = 0; i < 4; i++) {
        int r = row0 + i;
        if (r < N_NODES) {
            uint4 o;
            o.x = pk2(acc[i][0], acc[i][1]);
            o.y = pk2(acc[i][2], acc[i][3]);
            o.z = pk2(acc[i][4], acc[i][5]);
            o.w = pk2(acc[i][6], acc[i][7]);
            *(uint4*)&Bout[(size_t)r * 128 + c0] = o;
        }
    }
    // fused BN stats from fp32 acc
    float s8[8], q8[8];
    #pragma unroll
    for (int j = 0; j < 8; j++) { s8[j] = 0.f; q8[j] = 0.f; }
    #pragma unroll
    for (int i = 0; i < 4; i++) {
        if (row0 + i < N_NODES) {
            #pragma unroll
            for (int j = 0; j < 8; j++) {
                float v = acc[i][j];
                s8[j] += v; q8[j] += v * v;
            }
        }
    }
    __syncthreads();
    float* sSum = sW;              // [16][128]
    float* sSq  = sW + 16 * 128;   // [16][128]
    #pragma unroll
    for (int j = 0; j < 8; j++) {
        sSum[ty * 128 + c0 + j] = s8[j];
        sSq[ty * 128 + c0 + j]  = q8[j];
    }
    __syncthreads();
    if (tid < 128) {
        float s = 0.f;
        #pragma unroll
        for (int t = 0; t < 16; t++) s += sSum[t * 128 + tid];
        atomicAdd(&S[tid], s);
    } else {
        int c = tid - 128;
        float q = 0.f;
        #pragma unroll
        for (int t = 0; t < 16; t++) q += sSq[t * 128 + c];
        atomicAdd(&Q[c], q);
    }
}

__global__ void bnfin_kernel(const float* __restrict__ S, const float* __restrict__ Q,
                             const float* __restrict__ gamma, const float* __restrict__ beta,
                             float* __restrict__ ss) {
    int c = threadIdx.x;
    float mean = S[c] * (1.f / N_NODES);
    float var = fmaxf(Q[c] * (1.f / N_NODES) - mean * mean, 0.f);
    float sc = gamma[c] * rsqrtf(var + 1e-5f);
    ss[c] = sc;
    ss[D_HID + c] = beta[c] - mean * sc;
}

// ==================== GEMM2 ====================
// out[M,64] = relu(bn(h1))[M,128] @ W2[128,64] + b2 (+mish, bf16 out for L<3).
// A staged per 64-wide K-chunk in LDS with BN+relu applied during staging.
__device__ __forceinline__ float mish_f(float v) {
    if (v > 30.f) return v;
    float u = __expf(v);
    float t = (u + 1.f) * (u + 1.f);
    return v * (t - 1.f) / (t + 1.f);  // = v * tanh(softplus(v))
}

__global__ __launch_bounds__(256) void gemm2_kernel(const u16* __restrict__ H,
                                                    const float* __restrict__ ss,
                                                    const float* __restrict__ W,
                                                    const float* __restrict__ bias,
                                                    float* __restrict__ outf,
                                                    u16* __restrict__ outb,
                                                    int dobf16) {
    __shared__ float sW[128 * 64];  // 32 KB
    __shared__ float sA[64 * 65];   // 16.6 KB (64 rows x 64 k, padded)
    const int tid = threadIdx.x;
    const int row0g = blockIdx.x * 64;
    {
        const float4* Wv = (const float4*)W;
        float4* sWv = (float4*)sW;
        #pragma unroll
        for (int i = tid; i < 128 * 64 / 4; i += 256) sWv[i] = Wv[i];
    }
    const int tx = tid & 15;   // 16 col-groups of 4 -> 64 cols
    const int ty = tid >> 4;   // 16 row-groups of 4 -> 64 rows
    const int c0 = tx * 4;
    const int ty4 = ty * 4;
    const int row0 = row0g + ty4;

    float acc[4][4];
    #pragma unroll
    for (int i = 0; i < 4; i++)
        #pragma unroll
        for (int j = 0; j < 4; j++) acc[i][j] = bias[c0 + j];

    const u32* Hu = (const u32*)H;
    #pragma unroll
    for (int chunk = 0; chunk < 2; chunk++) {
        __syncthreads();  // protect previous sA (and sW store on first pass)
        // stage: 64 rows x 32 uints of this K-chunk, BN+relu applied
        #pragma unroll
        for (int i = tid; i < 64 * 32; i += 256) {
            int row = i >> 5, cu = i & 31;
            int grow = min(row0g + row, N_NODES - 1);
            u32 u = Hu[(size_t)grow * 64 + chunk * 32 + cu];
            int k = chunk * 64 + cu * 2;
            float v0 = fmaf(bf2f((u16)u),         ss[k],     ss[D_HID + k]);
            float v1 = fmaf(bf2f((u16)(u >> 16)), ss[k + 1], ss[D_HID + k + 1]);
            sA[row * 65 + cu * 2]     = fmaxf(v0, 0.f);
            sA[row * 65 + cu * 2 + 1] = fmaxf(v1, 0.f);
        }
        __syncthreads();
        const int kb = chunk * 64;
        #pragma unroll
        for (int kl = 0; kl < 64; kl += 4) {
            #pragma unroll
            for (int kk = 0; kk < 4; kk++) {
                float4 w0 = *(const float4*)&sW[(kb + kl + kk) * 64 + c0];
                #pragma unroll
                for (int i = 0; i < 4; i++) {
                    float ai = sA[(ty4 + i) * 65 + kl + kk];
                    acc[i][0] = fmaf(ai, w0.x, acc[i][0]);
                    acc[i][1] = fmaf(ai, w0.y, acc[i][1]);
                    acc[i][2] = fmaf(ai, w0.z, acc[i][2]);
                    acc[i][3] = fmaf(ai, w0.w, acc[i][3]);
                }
            }
        }
    }
    #pragma unroll
    for (int i = 0; i < 4; i++) {
        int r = row0 + i;
        if (r < N_NODES) {
            if (dobf16) {
                float m0 = mish_f(acc[i][0]), m1 = mish_f(acc[i][1]);
                float m2 = mish_f(acc[i][2]), m3 = mish_f(acc[i][3]);
                *(uint2*)&outb[(size_t)r * 64 + c0] = make_uint2(pk2(m0, m1), pk2(m2, m3));
            } else {
                *(float4*)&outf[(size_t)r * 64 + c0] =
                    make_float4(acc[i][0], acc[i][1], acc[i][2], acc[i][3]);
            }
        }
    }
}

// ============================ launch ============================

extern "C" void kernel_launch(void* const* d_in, const int* in_sizes, int n_in,
                              void* d_out, int out_size, void* d_ws, size_t ws_size,
                              hipStream_t stream) {
    const float* x     = (const float*)d_in[0];
    const int*   ei    = (const int*)d_in[1];
    const float* W1    = (const float*)d_in[2];
    const float* b1    = (const float*)d_in[3];
    const float* gamma = (const float*)d_in[4];
    const float* beta  = (const float*)d_in[5];
    const float* W2    = (const float*)d_in[6];
    const float* b2    = (const float*)d_in[7];
    float* out = (float*)d_out;

    const int* src = ei;
    const int* dst = ei + N_EDGES;

    char* base = (char*)d_ws;
    size_t o = 0;
    auto take = [&](size_t bytes) -> char* {
        char* p = base + o;
        o = (o + bytes + 255) & ~(size_t)255;
        return p;
    };
    int* deg     = (int*)take((size_t)N_NODES * 4);
    int* off     = (int*)take((size_t)(N_NODES + 1) * 4);
    int* esrc    = (int*)take((size_t)N_EDGES * 4);
    int2* ebuf   = (int2*)take((size_t)N_EDGES * 8);
    int* bsum    = (int*)take((size_t)N_SB * 4);
    int* boff    = (int*)take((size_t)N_SB * 4);
    int* gcur    = (int*)take((size_t)NB * 4);
    float* bn    = (float*)take(512 * 4);  // S[128] Q[128] scale/shift[256]
    u16* xbuf    = (u16*)take((size_t)N_NODES * D_IN * 2);   // bf16 hidden state
    u16* hbuf    = (u16*)take((size_t)N_NODES * D_IN * 2);   // bf16 agg output
    u16* h1buf   = (u16*)take((size_t)N_NODES * D_HID * 2);  // bf16 mid activations

    // CSR build (once per call; dst is layer-invariant)
    hipMemsetAsync(deg, 0, (size_t)N_NODES * 4, stream);
    count_kernel<<<(N_EDGES + 255) / 256, 256, 0, stream>>>(dst, deg, N_EDGES);
    scan_reduce_kernel<<<N_SB, SCAN_B, 0, stream>>>(deg, bsum);
    scan_sums_kernel<<<1, SCAN_B, 0, stream>>>(bsum, boff);
    scan_write_kernel<<<N_SB, SCAN_B, 0, stream>>>(deg, boff, off);
    bin_init_kernel<<<1, 256, 0, stream>>>(off, gcur);
    bin_pass1_kernel<<<P1_BLOCKS, 256, 0, stream>>>(src, dst, gcur, ebuf);
    bin_pass2_kernel<<<NB, 256, 0, stream>>>(off, ebuf, esrc);
    xcvt_kernel<<<(N_NODES * D_IN / 4 + 255) / 256, 256, 0, stream>>>(x, xbuf);

    for (int L = 0; L < 4; L++) {
        agg_kernel<<<N_NODES / 4, 256, 0, stream>>>(xbuf, off, esrc, hbuf);
        hipMemsetAsync(bn, 0, 256 * 4, stream);  // zero S/Q before gemm1's fused stats
        gemm1_kernel<<<(N_NODES + 63) / 64, 256, 0, stream>>>(
            hbuf, W1 + (size_t)L * D_IN * D_HID, b1 + (size_t)L * D_HID, h1buf,
            bn, bn + 128);
        bnfin_kernel<<<1, 128, 0, stream>>>(bn, bn + 128, gamma + (size_t)L * D_HID,
                                            beta + (size_t)L * D_HID, bn + 256);
        gemm2_kernel<<<(N_NODES + 63) / 64, 256, 0, stream>>>(
            h1buf, bn + 256, W2 + (size_t)L * D_HID * D_IN, b2 + (size_t)L * D_IN,
            out, xbuf, (L < 3) ? 1 : 0);
    }
}

// Round 7
// 527.711 us; speedup vs baseline: 4.8791x; 4.8791x over previous
//
#include <hip/hip_runtime.h>
#include <math.h>

#define N_NODES 50000
#define N_EDGES 800000
#define D_IN 64
#define D_HID 128
#define SCAN_B 256
#define N_SB ((N_NODES + SCAN_B - 1) / SCAN_B)  // 196
#define NPB 256                                  // nodes per bucket
#define NB ((N_NODES + NPB - 1) / NPB)           // 196 buckets
#define P1_BLOCKS 256
#define EPB (N_EDGES / P1_BLOCKS)                // 3125 edges per pass-1 block

typedef unsigned short u16;
typedef unsigned int u32;

__device__ __forceinline__ float bf2f(u16 u) {
    u32 x = ((u32)u) << 16;
    float f; __builtin_memcpy(&f, &x, 4); return f;
}
__device__ __forceinline__ u16 f2bf(float f) {  // round-to-nearest-even
    u32 x; __builtin_memcpy(&x, &f, 4);
    x += 0x7fffu + ((x >> 16) & 1u);
    return (u16)(x >> 16);
}
__device__ __forceinline__ u32 pk2(float a, float b) {  // pack 2 bf16 into u32
    return (u32)f2bf(a) | ((u32)f2bf(b) << 16);
}

// ============================ CSR build ============================

__global__ void count_kernel(const int* __restrict__ dst, int* __restrict__ deg, int E) {
    int i = blockIdx.x * blockDim.x + threadIdx.x;
    if (i < E) atomicAdd(&deg[dst[i]], 1);
}

__global__ __launch_bounds__(SCAN_B) void scan_reduce_kernel(const int* __restrict__ deg,
                                                             int* __restrict__ bsum) {
    __shared__ int s[SCAN_B];
    int i = blockIdx.x * SCAN_B + threadIdx.x;
    int v = (i < N_NODES) ? deg[i] : 0;
    s[threadIdx.x] = v;
    __syncthreads();
    #pragma unroll
    for (int o = SCAN_B / 2; o > 0; o >>= 1) {
        if (threadIdx.x < o) s[threadIdx.x] += s[threadIdx.x + o];
        __syncthreads();
    }
    if (threadIdx.x == 0) bsum[blockIdx.x] = s[0];
}

__global__ __launch_bounds__(SCAN_B) void scan_sums_kernel(const int* __restrict__ bsum,
                                                           int* __restrict__ boff) {
    __shared__ int s[SCAN_B];
    int t = threadIdx.x;
    int v = (t < N_SB) ? bsum[t] : 0;
    s[t] = v;
    __syncthreads();
    #pragma unroll
    for (int o = 1; o < SCAN_B; o <<= 1) {
        int u = (t >= o) ? s[t - o] : 0;
        __syncthreads();
        s[t] += u;
        __syncthreads();
    }
    if (t < N_SB) boff[t] = s[t] - v;  // exclusive
}

__global__ __launch_bounds__(SCAN_B) void scan_write_kernel(const int* __restrict__ deg,
                                                            const int* __restrict__ boff,
                                                            int* __restrict__ off) {
    __shared__ int s[SCAN_B];
    int t = threadIdx.x;
    int i = blockIdx.x * SCAN_B + t;
    int v = (i < N_NODES) ? deg[i] : 0;
    s[t] = v;
    __syncthreads();
    #pragma unroll
    for (int o = 1; o < SCAN_B; o <<= 1) {
        int u = (t >= o) ? s[t - o] : 0;
        __syncthreads();
        s[t] += u;
        __syncthreads();
    }
    int incl = s[t] + boff[blockIdx.x];
    if (i < N_NODES) off[i] = incl - v;
    if (i == N_NODES - 1) off[N_NODES] = incl;
}

// ==================== binned scatter (2-pass) ====================
__global__ void bin_init_kernel(const int* __restrict__ off, int* __restrict__ gcur) {
    int b = threadIdx.x;
    if (b < NB) gcur[b] = off[min(b * NPB, N_NODES)];
}

__global__ __launch_bounds__(256) void bin_pass1_kernel(const int* __restrict__ src,
                                                        const int* __restrict__ dst,
                                                        int* __restrict__ gcur,
                                                        int2* __restrict__ ebuf) {
    __shared__ int hist[NB];
    __shared__ int base[NB];
    const int tid = threadIdx.x;
    const int e0 = blockIdx.x * EPB, e1 = e0 + EPB;
    for (int b = tid; b < NB; b += 256) hist[b] = 0;
    __syncthreads();
    for (int i = e0 + tid; i < e1; i += 256)
        atomicAdd(&hist[dst[i] >> 8], 1);
    __syncthreads();
    for (int b = tid; b < NB; b += 256) {
        base[b] = atomicAdd(&gcur[b], hist[b]);
        hist[b] = 0;  // reuse as block-local cursor
    }
    __syncthreads();
    for (int i = e0 + tid; i < e1; i += 256) {
        int d = dst[i];
        int b = d >> 8;
        int slot = base[b] + atomicAdd(&hist[b], 1);
        ebuf[slot] = make_int2(src[i], d);
    }
}

__global__ __launch_bounds__(256) void bin_pass2_kernel(const int* __restrict__ off,
                                                        const int2* __restrict__ ebuf,
                                                        int* __restrict__ esrc) {
    __shared__ int soff[NPB];
    __shared__ int cur[NPB];
    const int b = blockIdx.x;
    const int tid = threadIdx.x;
    const int n0 = b * NPB;
    soff[tid] = off[min(n0 + tid, N_NODES)];
    cur[tid] = 0;
    __syncthreads();
    const int e0 = soff[0];
    const int e1 = off[min(n0 + NPB, N_NODES)];
    for (int i = e0 + tid; i < e1; i += 256) {
        int2 p = ebuf[i];
        int dl = p.y - n0;
        int slot = soff[dl] + atomicAdd(&cur[dl], 1);
        esrc[slot] = p.x;
    }
}

// ==================== x -> bf16 convert ====================
__global__ __launch_bounds__(256) void xcvt_kernel(const float* __restrict__ x,
                                                   u16* __restrict__ xb) {
    int i = blockIdx.x * 256 + threadIdx.x;  // one float4 per thread
    if (i < N_NODES * D_IN / 4) {
        float4 v = ((const float4*)x)[i];
        u32 lo = pk2(v.x, v.y), hi = pk2(v.z, v.w);
        ((uint2*)xb)[i] = make_uint2(lo, hi);
    }
}

// ==================== softmax aggregation + residual (bf16 in/out) ============
// One wave per node, lane = channel. No-max softmax (values O(1), fp32-safe).
// 8-edge unroll -> 8 outstanding 128B row-gathers from a 6.4MB L2-resident array.
__global__ __launch_bounds__(256) void agg_kernel(const u16* __restrict__ x,
                                                  const int* __restrict__ off,
                                                  const int* __restrict__ esrc,
                                                  u16* __restrict__ h) {
    int node = blockIdx.x * 4 + (threadIdx.x >> 6);
    int lane = threadIdx.x & 63;
    if (node >= N_NODES) return;
    float xn = bf2f(x[(size_t)node * D_IN + lane]);  // residual
    int jb = off[node], je = off[node + 1];
    float s = 0.f, t = 0.f;
    int j = jb;
    for (; j + 8 <= je; j += 8) {
        int idx[8];
        #pragma unroll
        for (int u = 0; u < 8; u++) idx[u] = esrc[j + u];
        u16 v[8];
        #pragma unroll
        for (int u = 0; u < 8; u++) v[u] = x[(size_t)idx[u] * D_IN + lane];
        #pragma unroll
        for (int u = 0; u < 8; u++) {
            float msg = fmaxf(bf2f(v[u]), 0.f) + 1e-7f;
            float p = __expf(msg);
            s += p;
            t = fmaf(msg, p, t);
        }
    }
    for (; j < je; j++) {
        int sv = esrc[j];
        float msg = fmaxf(bf2f(x[(size_t)sv * D_IN + lane]), 0.f) + 1e-7f;
        float p = __expf(msg);
        s += p;
        t = fmaf(msg, p, t);
    }
    float agg = t / (s + 1e-16f);    // deg==0 -> 0
    h[(size_t)node * D_IN + lane] = f2bf(agg + xn);
}

// ==================== GEMM1 + fused BN stats (R4-proven shape) ====================
// h1[M,128](bf16) = A[M,64](bf16) @ W[64,128] + b. Global A loads, W in LDS.
__global__ __launch_bounds__(256) void gemm1_kernel(const u16* __restrict__ A,
                                                    const float* __restrict__ W,
                                                    const float* __restrict__ bias,
                                                    u16* __restrict__ Bout,
                                                    float* __restrict__ S,
                                                    float* __restrict__ Q) {
    __shared__ float sW[64 * 128];  // 32 KB; reused as reduction space in epilogue
    const int tid = threadIdx.x;
    {
        const float4* Wv = (const float4*)W;
        float4* sWv = (float4*)sW;
        #pragma unroll
        for (int i = tid; i < 64 * 128 / 4; i += 256) sWv[i] = Wv[i];
    }
    __syncthreads();
    const int tx = tid & 15;   // 16 col-groups of 8 -> 128 cols
    const int ty = tid >> 4;   // 16 row-groups of 4 -> 64 rows
    const int c0 = tx * 8;
    const int row0 = blockIdx.x * 64 + ty * 4;
    const u32* Au = (const u32*)A;  // row stride 32 u32

    float acc[4][8];
    #pragma unroll
    for (int i = 0; i < 4; i++)
        #pragma unroll
        for (int j = 0; j < 8; j++) acc[i][j] = bias[c0 + j];

    for (int k = 0; k < 64; k += 4) {
        float a[4][4];
        #pragma unroll
        for (int i = 0; i < 4; i++) {
            int r = min(row0 + i, N_NODES - 1);
            uint2 t2 = *(const uint2*)&Au[(size_t)r * 32 + (k >> 1)];
            a[i][0] = bf2f((u16)t2.x);
            a[i][1] = bf2f((u16)(t2.x >> 16));
            a[i][2] = bf2f((u16)t2.y);
            a[i][3] = bf2f((u16)(t2.y >> 16));
        }
        #pragma unroll
        for (int kk = 0; kk < 4; kk++) {
            float4 w0 = *(const float4*)&sW[(k + kk) * 128 + c0];
            float4 w1 = *(const float4*)&sW[(k + kk) * 128 + c0 + 4];
            #pragma unroll
            for (int i = 0; i < 4; i++) {
                float ai = a[i][kk];
                acc[i][0] = fmaf(ai, w0.x, acc[i][0]);
                acc[i][1] = fmaf(ai, w0.y, acc[i][1]);
                acc[i][2] = fmaf(ai, w0.z, acc[i][2]);
                acc[i][3] = fmaf(ai, w0.w, acc[i][3]);
                acc[i][4] = fmaf(ai, w1.x, acc[i][4]);
                acc[i][5] = fmaf(ai, w1.y, acc[i][5]);
                acc[i][6] = fmaf(ai, w1.z, acc[i][6]);
                acc[i][7] = fmaf(ai, w1.w, acc[i][7]);
            }
        }
    }
    // store bf16 tile
    #pragma unroll
    for (int i = 0; i < 4; i++) {
        int r = row0 + i;
        if (r < N_NODES) {
            uint4 o;
            o.x = pk2(acc[i][0], acc[i][1]);
            o.y = pk2(acc[i][2], acc[i][3]);
            o.z = pk2(acc[i][4], acc[i][5]);
            o.w = pk2(acc[i][6], acc[i][7]);
            *(uint4*)&Bout[(size_t)r * 128 + c0] = o;
        }
    }
    // fused BN stats from fp32 acc
    float s8[8], q8[8];
    #pragma unroll
    for (int j = 0; j < 8; j++) { s8[j] = 0.f; q8[j] = 0.f; }
    #pragma unroll
    for (int i = 0; i < 4; i++) {
        if (row0 + i < N_NODES) {
            #pragma unroll
            for (int j = 0; j < 8; j++) {
                float v = acc[i][j];
                s8[j] += v; q8[j] += v * v;
            }
        }
    }
    __syncthreads();
    float* sSum = sW;              // [16][128]
    float* sSq  = sW + 16 * 128;   // [16][128]
    #pragma unroll
    for (int j = 0; j < 8; j++) {
        sSum[ty * 128 + c0 + j] = s8[j];
        sSq[ty * 128 + c0 + j]  = q8[j];
    }
    __syncthreads();
    if (tid < 128) {
        float s = 0.f;
        #pragma unroll
        for (int t = 0; t < 16; t++) s += sSum[t * 128 + tid];
        atomicAdd(&S[tid], s);
    } else {
        int c = tid - 128;
        float q = 0.f;
        #pragma unroll
        for (int t = 0; t < 16; t++) q += sSq[t * 128 + c];
        atomicAdd(&Q[c], q);
    }
}

__global__ void bnfin_kernel(const float* __restrict__ S, const float* __restrict__ Q,
                             const float* __restrict__ gamma, const float* __restrict__ beta,
                             float* __restrict__ ss) {
    int c = threadIdx.x;
    float mean = S[c] * (1.f / N_NODES);
    float var = fmaxf(Q[c] * (1.f / N_NODES) - mean * mean, 0.f);
    float sc = gamma[c] * rsqrtf(var + 1e-5f);
    ss[c] = sc;
    ss[D_HID + c] = beta[c] - mean * sc;
}

// ==================== GEMM2 (R4-proven shape) ====================
// out[M,64] = relu(bn(h1))[M,128](bf16) @ W2[128,64] + b2 (+mish).
__device__ __forceinline__ float mish_f(float v) {
    if (v > 30.f) return v;
    float u = __expf(v);
    float t = (u + 1.f) * (u + 1.f);
    return v * (t - 1.f) / (t + 1.f);  // = v * tanh(softplus(v))
}

__global__ __launch_bounds__(256) void gemm2_kernel(const u16* __restrict__ H,
                                                    const float* __restrict__ ss,
                                                    const float* __restrict__ W,
                                                    const float* __restrict__ bias,
                                                    float* __restrict__ outf,
                                                    u16* __restrict__ outb,
                                                    int dobf16) {
    __shared__ float sW[128 * 64];  // 32 KB
    const int tid = threadIdx.x;
    {
        const float4* Wv = (const float4*)W;
        float4* sWv = (float4*)sW;
        #pragma unroll
        for (int i = tid; i < 128 * 64 / 4; i += 256) sWv[i] = Wv[i];
    }
    __syncthreads();
    const int tx = tid & 7;    // 8 col-groups of 8 -> 64 cols
    const int ty = tid >> 3;   // 32 row-groups of 4 -> 128 rows
    const int c0 = tx * 8;
    const int row0 = blockIdx.x * 128 + ty * 4;
    const u32* Hu = (const u32*)H;  // row stride 64 u32

    float acc[4][8];
    #pragma unroll
    for (int i = 0; i < 4; i++)
        #pragma unroll
        for (int j = 0; j < 8; j++) acc[i][j] = bias[c0 + j];

    for (int k = 0; k < 128; k += 4) {
        float4 sc4 = *(const float4*)&ss[k];
        float4 sh4 = *(const float4*)&ss[D_HID + k];
        float a[4][4];
        #pragma unroll
        for (int i = 0; i < 4; i++) {
            int r = min(row0 + i, N_NODES - 1);
            uint2 t2 = *(const uint2*)&Hu[(size_t)r * 64 + (k >> 1)];
            a[i][0] = fmaxf(fmaf(bf2f((u16)t2.x),         sc4.x, sh4.x), 0.f);
            a[i][1] = fmaxf(fmaf(bf2f((u16)(t2.x >> 16)), sc4.y, sh4.y), 0.f);
            a[i][2] = fmaxf(fmaf(bf2f((u16)t2.y),         sc4.z, sh4.z), 0.f);
            a[i][3] = fmaxf(fmaf(bf2f((u16)(t2.y >> 16)), sc4.w, sh4.w), 0.f);
        }
        #pragma unroll
        for (int kk = 0; kk < 4; kk++) {
            float4 w0 = *(const float4*)&sW[(k + kk) * 64 + c0];
            float4 w1 = *(const float4*)&sW[(k + kk) * 64 + c0 + 4];
            #pragma unroll
            for (int i = 0; i < 4; i++) {
                float ai = a[i][kk];
                acc[i][0] = fmaf(ai, w0.x, acc[i][0]);
                acc[i][1] = fmaf(ai, w0.y, acc[i][1]);
                acc[i][2] = fmaf(ai, w0.z, acc[i][2]);
                acc[i][3] = fmaf(ai, w0.w, acc[i][3]);
                acc[i][4] = fmaf(ai, w1.x, acc[i][4]);
                acc[i][5] = fmaf(ai, w1.y, acc[i][5]);
                acc[i][6] = fmaf(ai, w1.z, acc[i][6]);
                acc[i][7] = fmaf(ai, w1.w, acc[i][7]);
            }
        }
    }
    #pragma unroll
    for (int i = 0; i < 4; i++) {
        int r = row0 + i;
        if (r < N_NODES) {
            if (dobf16) {
                uint4 o;
                o.x = pk2(mish_f(acc[i][0]), mish_f(acc[i][1]));
                o.y = pk2(mish_f(acc[i][2]), mish_f(acc[i][3]));
                o.z = pk2(mish_f(acc[i][4]), mish_f(acc[i][5]));
                o.w = pk2(mish_f(acc[i][6]), mish_f(acc[i][7]));
                *(uint4*)&outb[(size_t)r * 64 + c0] = o;
            } else {
                *(float4*)&outf[(size_t)r * 64 + c0] =
                    make_float4(acc[i][0], acc[i][1], acc[i][2], acc[i][3]);
                *(float4*)&outf[(size_t)r * 64 + c0 + 4] =
                    make_float4(acc[i][4], acc[i][5], acc[i][6], acc[i][7]);
            }
        }
    }
}

// ============================ launch ============================

extern "C" void kernel_launch(void* const* d_in, const int* in_sizes, int n_in,
                              void* d_out, int out_size, void* d_ws, size_t ws_size,
                              hipStream_t stream) {
    const float* x     = (const float*)d_in[0];
    const int*   ei    = (const int*)d_in[1];
    const float* W1    = (const float*)d_in[2];
    const float* b1    = (const float*)d_in[3];
    const float* gamma = (const float*)d_in[4];
    const float* beta  = (const float*)d_in[5];
    const float* W2    = (const float*)d_in[6];
    const float* b2    = (const float*)d_in[7];
    float* out = (float*)d_out;

    const int* src = ei;
    const int* dst = ei + N_EDGES;

    char* base = (char*)d_ws;
    size_t o = 0;
    auto take = [&](size_t bytes) -> char* {
        char* p = base + o;
        o = (o + bytes + 255) & ~(size_t)255;
        return p;
    };
    int* deg     = (int*)take((size_t)N_NODES * 4);
    int* off     = (int*)take((size_t)(N_NODES + 1) * 4);
    int* esrc    = (int*)take((size_t)N_EDGES * 4);
    int2* ebuf   = (int2*)take((size_t)N_EDGES * 8);
    int* bsum    = (int*)take((size_t)N_SB * 4);
    int* boff    = (int*)take((size_t)N_SB * 4);
    int* gcur    = (int*)take((size_t)NB * 4);
    float* bn    = (float*)take(512 * 4);  // S[128] Q[128] scale/shift[256]
    u16* xbuf    = (u16*)take((size_t)N_NODES * D_IN * 2);   // bf16 hidden state
    u16* hbuf    = (u16*)take((size_t)N_NODES * D_IN * 2);   // bf16 agg output
    u16* h1buf   = (u16*)take((size_t)N_NODES * D_HID * 2);  // bf16 mid activations

    // CSR build (once per call; dst is layer-invariant)
    hipMemsetAsync(deg, 0, (size_t)N_NODES * 4, stream);
    count_kernel<<<(N_EDGES + 255) / 256, 256, 0, stream>>>(dst, deg, N_EDGES);
    scan_reduce_kernel<<<N_SB, SCAN_B, 0, stream>>>(deg, bsum);
    scan_sums_kernel<<<1, SCAN_B, 0, stream>>>(bsum, boff);
    scan_write_kernel<<<N_SB, SCAN_B, 0, stream>>>(deg, boff, off);
    bin_init_kernel<<<1, 256, 0, stream>>>(off, gcur);
    bin_pass1_kernel<<<P1_BLOCKS, 256, 0, stream>>>(src, dst, gcur, ebuf);
    bin_pass2_kernel<<<NB, 256, 0, stream>>>(off, ebuf, esrc);
    xcvt_kernel<<<(N_NODES * D_IN / 4 + 255) / 256, 256, 0, stream>>>(x, xbuf);

    for (int L = 0; L < 4; L++) {
        agg_kernel<<<N_NODES / 4, 256, 0, stream>>>(xbuf, off, esrc, hbuf);
        hipMemsetAsync(bn, 0, 256 * 4, stream);  // zero S/Q before gemm1's fused stats
        gemm1_kernel<<<(N_NODES + 63) / 64, 256, 0, stream>>>(
            hbuf, W1 + (size_t)L * D_IN * D_HID, b1 + (size_t)L * D_HID, h1buf,
            bn, bn + 128);
        bnfin_kernel<<<1, 128, 0, stream>>>(bn, bn + 128, gamma + (size_t)L * D_HID,
                                            beta + (size_t)L * D_HID, bn + 256);
        gemm2_kernel<<<(N_NODES + 127) / 128, 256, 0, stream>>>(
            h1buf, bn + 256, W2 + (size_t)L * D_HID * D_IN, b2 + (size_t)L * D_IN,
            out, xbuf, (L < 3) ? 1 : 0);
    }
}